// Round 1
// baseline (1794.602 us; speedup 1.0000x reference)
//
#include <hip/hip_runtime.h>
#include <hip/hip_cooperative_groups.h>

namespace cg = cooperative_groups;

#define NCH 6
#define NCELL (32 * 32 * 32)      // 32768 cells
#define CH_STRIDE NCELL           // channel stride in phi buffers
#define STEP_STRIDE (NCH * NCELL) // 196608 floats per history step

// One cooperative kernel runs the whole 300-step CA.
// Layout: phi[ch][x][y][z] flat, cell = x*1024 + y*32 + z.
// Each thread owns one cell and computes all 6 channels of nxt there:
//   nxt[o,cell] = clip( sum_i (D[o,i,nb_o]+0.95) * phi[i,nb_o] ), nb_o = cell shifted
// Double-buffered phi in d_ws -> one grid.sync() per step.
// Once the wave reaches (ex,ey,ez), phi is frozen; we break out and bulk-fill
// the remaining history slices (memory-bound coalesced stores).
__global__ void BEMNA_V7_2_PhaseSpace_44117904064519_kernel(
    const float* __restrict__ D,
    const int* __restrict__ sx_p, const int* __restrict__ sy_p,
    const int* __restrict__ sz_p, const int* __restrict__ ex_p,
    const int* __restrict__ ey_p, const int* __restrict__ ez_p,
    const int* __restrict__ maxit_p,
    float* __restrict__ out,
    float* __restrict__ phi_a,
    float* __restrict__ phi_b,
    int* __restrict__ flags)
{
    cg::grid_group grid = cg::this_grid();
    const int cell = blockIdx.x * blockDim.x + threadIdx.x;  // 0..32767
    const int x = cell >> 10;
    const int y = (cell >> 5) & 31;
    const int z = cell & 31;

    const int sx = *sx_p, sy = *sy_p, sz = *sz_p;
    const int ex = *ex_p, ey = *ey_p, ez = *ez_p;
    const int maxit = *maxit_p;
    const int seed = (sx << 10) | (sy << 5) | sz;
    const bool is_target = (x == ex) && (y == ey) && (z == ez);

    // ---- init: phi0 = 0 except all 6 channels = 1 at the seed cell ----
    const float init_v = (cell == seed) ? 1.0f : 0.0f;
#pragma unroll
    for (int o = 0; o < NCH; ++o) phi_a[o * CH_STRIDE + cell] = init_v;
    if (cell == 0) {
        __hip_atomic_store(&flags[0], 0, __ATOMIC_RELAXED, __HIP_MEMORY_SCOPE_AGENT);
    }
    grid.sync();

    float* cur = phi_a;
    float* nxt = phi_b;

    // neighbor linear offsets per out-channel and bounds checks
    // o=0:+x shift -> read (x-1); o=1:-x -> (x+1); o=2:(y-1); o=3:(y+1); o=4:(z-1); o=5:(z+1)
    const int nb[NCH]  = { cell - 1024, cell + 1024, cell - 32, cell + 32, cell - 1, cell + 1 };
    const bool ok[NCH] = { x >= 1, x <= 30, y >= 1, y <= 30, z >= 1, z <= 30 };

    int t = 0;
    for (; t < maxit; ++t) {
        // history[t] = phi (pre-update)
        float* outp = out + (size_t)t * STEP_STRIDE + cell;
#pragma unroll
        for (int o = 0; o < NCH; ++o)
            outp[o * CH_STRIDE] = cur[o * CH_STRIDE + cell];

        const int done =
            __hip_atomic_load(&flags[0], __ATOMIC_RELAXED, __HIP_MEMORY_SCOPE_AGENT);
        if (done) break;  // uniform across all threads (flag set before last sync)

        // compute nxt for this cell, all 6 channels
        float v[NCH];
#pragma unroll
        for (int o = 0; o < NCH; ++o) {
            float val = 0.0f;
            if (ok[o]) {
                const int n = nb[o];
                float acc = 0.0f;
#pragma unroll
                for (int i = 0; i < NCH; ++i) {
                    const float d = D[(size_t)(o * NCH + i) * CH_STRIDE + n] + 0.95f;
                    acc = fmaf(d, cur[i * CH_STRIDE + n], acc);
                }
                val = fminf(fmaxf(acc, 0.0f), 1.0f);
            }
            v[o] = val;
            nxt[o * CH_STRIDE + cell] = val;
        }

        if (is_target) {
            const float s = v[0] + v[1] + v[2] + v[3] + v[4] + v[5];
            if (s > 0.01f)
                __hip_atomic_store(&flags[0], 1, __ATOMIC_RELAXED, __HIP_MEMORY_SCOPE_AGENT);
        }

        grid.sync();  // makes nxt + flag visible device-wide
        float* tmp = cur; cur = nxt; nxt = tmp;
    }

    // ---- fill phase: phi frozen, remaining history slices are identical ----
    if (t < maxit) {
        float h[NCH];
#pragma unroll
        for (int o = 0; o < NCH; ++o) h[o] = cur[o * CH_STRIDE + cell];
        for (int tt = t + 1; tt < maxit; ++tt) {
            float* outp = out + (size_t)tt * STEP_STRIDE + cell;
#pragma unroll
            for (int o = 0; o < NCH; ++o)
                outp[o * CH_STRIDE] = h[o];
        }
    }
}

extern "C" void kernel_launch(void* const* d_in, const int* in_sizes, int n_in,
                              void* d_out, int out_size, void* d_ws, size_t ws_size,
                              hipStream_t stream)
{
    const float* D   = (const float*)d_in[0];
    const int* sx    = (const int*)d_in[1];
    const int* sy    = (const int*)d_in[2];
    const int* sz    = (const int*)d_in[3];
    const int* ex    = (const int*)d_in[4];
    const int* ey    = (const int*)d_in[5];
    const int* ez    = (const int*)d_in[6];
    const int* maxit = (const int*)d_in[7];
    float* out = (float*)d_out;

    // workspace layout: phi_a | phi_b | flags  (~1.6 MB; ws re-poisoned each
    // launch, so everything is (re)initialized inside the kernel)
    float* phi_a = (float*)d_ws;
    float* phi_b = phi_a + (size_t)NCH * NCELL;
    int* flags   = (int*)(phi_b + (size_t)NCH * NCELL);

    void* args[] = { &D, &sx, &sy, &sz, &ex, &ey, &ez, &maxit,
                     &out, &phi_a, &phi_b, &flags };

    // 128 blocks x 256 threads = 32768 threads = 1 thread/cell.
    // Cooperative launch: grid.sync() between CA steps.
    hipLaunchCooperativeKernel(
        (void*)BEMNA_V7_2_PhaseSpace_44117904064519_kernel,
        dim3(128), dim3(256), args, 0, stream);
}

// Round 2
// 1632.078 us; speedup vs baseline: 1.0996x; 1.0996x over previous
//
#include <hip/hip_runtime.h>
#include <hip/hip_cooperative_groups.h>

namespace cg = cooperative_groups;

#define NCH 6
#define NCELL (32 * 32 * 32)      // 32768 cells
#define CH_STRIDE NCELL           // channel stride in phi buffers
#define STEP_STRIDE (NCH * NCELL) // 196608 floats per history step
#define NBLOCKS 128
#define NTHREADS 256

// flags layout in ws (after phi_a|phi_b):
//   [0] done flag   [1] t_freeze   [2] parity   [8] barrier counter   [9] barrier gen
#define F_DONE 0
#define F_TFREEZE 1
#define F_PARITY 2
#define F_BARCNT 8
#define F_BARGEN 9

// Hand-rolled sense-reversing grid barrier, agent scope.
// Rationale: cg::grid.sync() measured ~17.8 us/step (R1: 1600us/90 steps with
// ~1us of real work per step). Classic two-phase barrier: __syncthreads drains
// each thread's stores to L2 (vmcnt 0); thread 0's ACQ_REL fetch_add releases
// the block's writes device-wide; last arrival RELEASEs gen; spinners ACQUIRE
// gen (invalidates L1) -> all pre-barrier writes visible to all post-barrier
// reads by release-acquire transitivity through the counter.
__device__ __forceinline__ void grid_barrier(int* counter, int* gen) {
    __syncthreads();
    if (threadIdx.x == 0) {
        const int g = __hip_atomic_load(gen, __ATOMIC_RELAXED, __HIP_MEMORY_SCOPE_AGENT);
        const int arrived = __hip_atomic_fetch_add(counter, 1, __ATOMIC_ACQ_REL,
                                                   __HIP_MEMORY_SCOPE_AGENT);
        if (arrived == NBLOCKS - 1) {
            __hip_atomic_store(counter, 0, __ATOMIC_RELAXED, __HIP_MEMORY_SCOPE_AGENT);
            __hip_atomic_store(gen, g + 1, __ATOMIC_RELEASE, __HIP_MEMORY_SCOPE_AGENT);
        } else {
            while (__hip_atomic_load(gen, __ATOMIC_ACQUIRE, __HIP_MEMORY_SCOPE_AGENT) == g) {
                __builtin_amdgcn_s_sleep(1);
            }
        }
    }
    __syncthreads();
}

__global__ void BEMNA_V7_2_PhaseSpace_44117904064519_kernel(
    const float* __restrict__ D,
    const int* __restrict__ sx_p, const int* __restrict__ sy_p,
    const int* __restrict__ sz_p, const int* __restrict__ ex_p,
    const int* __restrict__ ey_p, const int* __restrict__ ez_p,
    const int* __restrict__ maxit_p,
    float* __restrict__ out,
    float* __restrict__ phi_a,
    float* __restrict__ phi_b,
    int* __restrict__ flags)
{
    cg::grid_group grid = cg::this_grid();
    const int cell = blockIdx.x * blockDim.x + threadIdx.x;  // 0..32767
    const int x = cell >> 10;
    const int y = (cell >> 5) & 31;
    const int z = cell & 31;

    const int sx = *sx_p, sy = *sy_p, sz = *sz_p;
    const int ex = *ex_p, ey = *ey_p, ez = *ez_p;
    const int maxit = *maxit_p;
    const int seed = (sx << 10) | (sy << 5) | sz;
    const bool is_target = (x == ex) && (y == ey) && (z == ez);

    // ---- init: phi0 = 0 except all 6 channels = 1 at the seed cell ----
    const float init_v = (cell == seed) ? 1.0f : 0.0f;
#pragma unroll
    for (int o = 0; o < NCH; ++o) phi_a[o * CH_STRIDE + cell] = init_v;
    if (cell == 0) {
        flags[F_DONE]   = 0;
        flags[F_BARCNT] = 0;
        flags[F_BARGEN] = 0;
    }
    // one cg sync to publish init (incl. barrier counters) before using the
    // custom barrier; avoids bootstrap race on the hand-rolled one
    grid.sync();

    float* cur = phi_a;
    float* nxt = phi_b;

    // neighbor linear offsets per out-channel and bounds checks
    // o=0:+x shift -> read (x-1); o=1:-x -> (x+1); o=2:(y-1); o=3:(y+1); o=4:(z-1); o=5:(z+1)
    const int nb[NCH]  = { cell - 1024, cell + 1024, cell - 32, cell + 32, cell - 1, cell + 1 };
    const bool ok[NCH] = { x >= 1, x <= 30, y >= 1, y <= 30, z >= 1, z <= 30 };

    // D is step-invariant: hoist all 36 (D+0.95) coefficients into registers
    float dreg[NCH][NCH];
#pragma unroll
    for (int o = 0; o < NCH; ++o) {
#pragma unroll
        for (int i = 0; i < NCH; ++i) {
            dreg[o][i] = ok[o]
                ? D[(size_t)(o * NCH + i) * CH_STRIDE + nb[o]] + 0.95f
                : 0.0f;
        }
    }

    int* bar_cnt = &flags[F_BARCNT];
    int* bar_gen = &flags[F_BARGEN];

    int t = 0;
    for (; t < maxit; ++t) {
        // history[t] = phi (pre-update)
        float* outp = out + (size_t)t * STEP_STRIDE + cell;
#pragma unroll
        for (int o = 0; o < NCH; ++o)
            outp[o * CH_STRIDE] = cur[o * CH_STRIDE + cell];

        const int done =
            __hip_atomic_load(&flags[F_DONE], __ATOMIC_RELAXED, __HIP_MEMORY_SCOPE_AGENT);
        if (done) break;  // uniform: flag last changed before the previous barrier

        // compute nxt for this cell, all 6 channels
        float v[NCH];
#pragma unroll
        for (int o = 0; o < NCH; ++o) {
            float val = 0.0f;
            if (ok[o]) {
                const int n = nb[o];
                float acc = 0.0f;
#pragma unroll
                for (int i = 0; i < NCH; ++i)
                    acc = fmaf(dreg[o][i], cur[i * CH_STRIDE + n], acc);
                val = fminf(fmaxf(acc, 0.0f), 1.0f);
            }
            v[o] = val;
            nxt[o * CH_STRIDE + cell] = val;
        }

        if (is_target) {
            const float s = v[0] + v[1] + v[2] + v[3] + v[4] + v[5];
            if (s > 0.01f)
                __hip_atomic_store(&flags[F_DONE], 1, __ATOMIC_RELAXED,
                                   __HIP_MEMORY_SCOPE_AGENT);
        }

        grid_barrier(bar_cnt, bar_gen);  // publish nxt + flag device-wide
        float* tmp = cur; cur = nxt; nxt = tmp;
    }

    // record freeze point for the fill kernel (end-of-kernel flush publishes)
    if (cell == 0) {
        flags[F_TFREEZE] = t;          // slices 0..t (inclusive) are written
        flags[F_PARITY]  = t & 1;      // frozen phi lives in (t&1) ? phi_b : phi_a
    }
}

// Fat fill kernel: slices t_freeze+1 .. maxit-1 are all the frozen phi.
// One float4 store per thread; pure streaming-write bandwidth.
__global__ void fill_kernel(const int* __restrict__ flags,
                            const float* __restrict__ phi_a,
                            const float* __restrict__ phi_b,
                            float4* __restrict__ out,
                            int total4)
{
    const int idx4 = blockIdx.x * blockDim.x + threadIdx.x;
    if (idx4 >= total4) return;
    const int t_freeze = flags[F_TFREEZE];
    const int t = idx4 / (STEP_STRIDE / 4);          // slice index
    if (t <= t_freeze) return;                        // already written by stepper
    const int r4 = idx4 - t * (STEP_STRIDE / 4);
    const float4* frozen = (const float4*)(flags[F_PARITY] ? phi_b : phi_a);
    out[idx4] = frozen[r4];
}

extern "C" void kernel_launch(void* const* d_in, const int* in_sizes, int n_in,
                              void* d_out, int out_size, void* d_ws, size_t ws_size,
                              hipStream_t stream)
{
    const float* D   = (const float*)d_in[0];
    const int* sx    = (const int*)d_in[1];
    const int* sy    = (const int*)d_in[2];
    const int* sz    = (const int*)d_in[3];
    const int* ex    = (const int*)d_in[4];
    const int* ey    = (const int*)d_in[5];
    const int* ez    = (const int*)d_in[6];
    const int* maxit = (const int*)d_in[7];
    float* out = (float*)d_out;

    // workspace layout: phi_a | phi_b | flags (ws re-poisoned each launch;
    // everything is (re)initialized inside the stepping kernel)
    float* phi_a = (float*)d_ws;
    float* phi_b = phi_a + (size_t)NCH * NCELL;
    int* flags   = (int*)(phi_b + (size_t)NCH * NCELL);

    void* args[] = { &D, &sx, &sy, &sz, &ex, &ey, &ez, &maxit,
                     &out, &phi_a, &phi_b, &flags };

    // 128 blocks x 256 threads = 1 thread/cell; cooperative so co-residency
    // is guaranteed for the hand-rolled grid barrier.
    hipLaunchCooperativeKernel(
        (void*)BEMNA_V7_2_PhaseSpace_44117904064519_kernel,
        dim3(NBLOCKS), dim3(NTHREADS), args, 0, stream);

    // host knows maxit implicitly: out_size = maxit * STEP_STRIDE
    const int total4 = out_size / 4;
    const int fill_blocks = (total4 + 255) / 256;
    fill_kernel<<<dim3(fill_blocks), dim3(256), 0, stream>>>(
        flags, phi_a, phi_b, (float4*)out, total4);
}

// Round 3
// 539.524 us; speedup vs baseline: 3.3263x; 3.0250x over previous
//
#include <hip/hip_runtime.h>

#define NCH 6
#define NX 32
#define PLANE 1024                 // 32*32 cells per x-plane
#define NCELL (NX * PLANE)
#define CH_STRIDE NCELL
#define STEP_STRIDE (NCH * NCELL)
#define NBLOCKS NX                 // one block per x-plane
#define NTHREADS PLANE

// flags layout (ints) in ws after phi_a|phi_b. All cross-block flags are
// accessed with sc0 sc1 (system-scope relaxed) -> live at L3, no L2 coherence
// traffic. Slots padded to one 64B line each.
#define F_DONE 0
#define F_TFREEZE 1
#define F_PARITY 2
#define F_GEN 16
#define F_SLOTS 32                 // slot b at F_SLOTS + b*16, b in [0,32)

__device__ __forceinline__ float ld_coh(const float* p) {
    return __hip_atomic_load(p, __ATOMIC_RELAXED, __HIP_MEMORY_SCOPE_SYSTEM);
}
__device__ __forceinline__ void st_coh(float* p, float v) {
    __hip_atomic_store(p, v, __ATOMIC_RELAXED, __HIP_MEMORY_SCOPE_SYSTEM);
}
__device__ __forceinline__ int ld_cohi(const int* p) {
    return __hip_atomic_load(p, __ATOMIC_RELAXED, __HIP_MEMORY_SCOPE_SYSTEM);
}
__device__ __forceinline__ void st_cohi(int* p, int v) {
    __hip_atomic_store(p, v, __ATOMIC_RELAXED, __HIP_MEMORY_SCOPE_SYSTEM);
}

// Flat-flag grid barrier: no atomic RMW (R2 showed 128 RMWs on one line cost
// ~16us/step), no acquire/release cache ops (all shared data is sc1 already).
// Caller must __syncthreads() BEFORE (drains each wave's sc1 stores to the L3
// coherence point) and AFTER (publishes smem_done block-wide).
// want is monotonically increasing; ws re-poison (0xAAAAAAAA = negative int)
// makes the signed >= comparisons safe at bootstrap.
__device__ __forceinline__ void grid_barrier(int want, int* flags, int* smem_done) {
    if (blockIdx.x == 0) {
        if (threadIdx.x < 64) {          // master wave polls all slots in parallel
            const int idx = (int)threadIdx.x & 31;
            const int* slot = &flags[F_SLOTS + idx * 16];
            for (;;) {
                const int v = (idx == 0) ? want : ld_cohi(slot);  // block 0 arrives implicitly
                if (__ballot(v >= want) == ~0ull) break;
                __builtin_amdgcn_s_sleep(1);
            }
            if (threadIdx.x == 0) {
                st_cohi(&flags[F_GEN], want);
                *smem_done = (ld_cohi(&flags[F_DONE]) == 1);
            }
        }
    } else if (threadIdx.x == 0) {
        st_cohi(&flags[F_SLOTS + (int)blockIdx.x * 16], want);
        while (ld_cohi(&flags[F_GEN]) < want)
            __builtin_amdgcn_s_sleep(1);
        *smem_done = (ld_cohi(&flags[F_DONE]) == 1);
    }
}

// One block per x-plane: y/z neighbor channels (o=2..5) are intra-block -> LDS;
// only x+-1 planes (o=0,1) cross blocks -> 12 sc1 loads/thread/step from L3.
__global__ void __launch_bounds__(NTHREADS, 1)
BEMNA_V7_2_PhaseSpace_44117904064519_kernel(
    const float* __restrict__ D,
    const int* __restrict__ sx_p, const int* __restrict__ sy_p,
    const int* __restrict__ sz_p, const int* __restrict__ ex_p,
    const int* __restrict__ ey_p, const int* __restrict__ ez_p,
    const int* __restrict__ maxit_p,
    float* __restrict__ out,
    float* __restrict__ phi_a,
    float* __restrict__ phi_b,
    int* __restrict__ flags)
{
    __shared__ float lds[2][NCH][PLANE];   // ping-pong plane buffers, 48 KB
    __shared__ int smem_done;

    const int tid = (int)threadIdx.x;      // y*32+z
    const int xb  = (int)blockIdx.x;       // plane index = x
    const int y = tid >> 5;
    const int z = tid & 31;
    const int cell = xb * PLANE + tid;

    const int sx = *sx_p, sy = *sy_p, sz = *sz_p;
    const int ex = *ex_p, ey = *ey_p, ez = *ez_p;
    const int maxit = *maxit_p;
    const bool is_seed   = (xb == sx) && (tid == ((sy << 5) | sz));
    const bool is_target = (xb == ex) && (tid == ((ey << 5) | ez));

    // o=0:+x shift reads (x-1); o=1 reads (x+1); o=2:(y-1); o=3:(y+1); o=4:(z-1); o=5:(z+1)
    const int  nbg[NCH] = { cell - PLANE, cell + PLANE, cell - 32, cell + 32, cell - 1, cell + 1 };
    const bool ok[NCH]  = { xb >= 1, xb <= NX - 2, y >= 1, y <= 30, z >= 1, z <= 30 };
    const int  nbl[4]   = { tid - 32, tid + 32, tid - 1, tid + 1 };  // for o=2..5 in LDS

    // D step-invariant: hoist 36 coefficients (plain loads, read-only input)
    float dreg[NCH][NCH];
#pragma unroll
    for (int o = 0; o < NCH; ++o)
#pragma unroll
        for (int i = 0; i < NCH; ++i)
            dreg[o][i] = ok[o] ? D[(size_t)(o * NCH + i) * CH_STRIDE + nbg[o]] + 0.95f : 0.0f;

    // ---- init: phi0 = seed cell all-ones ----
    float myv[NCH];
    float* cur = phi_a;
    float* nxt = phi_b;
    int buf = 0;
    const float init_v = is_seed ? 1.0f : 0.0f;
#pragma unroll
    for (int o = 0; o < NCH; ++o) {
        myv[o] = init_v;
        st_coh(&cur[o * CH_STRIDE + cell], init_v);
        lds[0][o][tid] = init_v;
    }
    if (tid == 0) smem_done = 0;
    __syncthreads();                 // drain init stores (vmcnt + lds)
    grid_barrier(1, flags, &smem_done);  // publish init planes (done still poisoned != 1 -> false)
    __syncthreads();

    int t = 0;
    for (; t < maxit; ++t) {
        // issue cross-plane loads early to overlap with history stores
        float pm[NCH], pp[NCH];
#pragma unroll
        for (int i = 0; i < NCH; ++i) {
            pm[i] = ok[0] ? ld_coh(&cur[i * CH_STRIDE + cell - PLANE]) : 0.0f;
            pp[i] = ok[1] ? ld_coh(&cur[i * CH_STRIDE + cell + PLANE]) : 0.0f;
        }

        // history[t] = phi (pre-update) straight from registers
        float* outp = out + (size_t)t * STEP_STRIDE + cell;
#pragma unroll
        for (int o = 0; o < NCH; ++o)
            outp[o * CH_STRIDE] = myv[o];

        if (smem_done) break;   // uniform: published at previous barrier

        float v[NCH];
        {   // o=0,1 from adjacent planes (L3)
            float a0 = 0.0f, a1 = 0.0f;
#pragma unroll
            for (int i = 0; i < NCH; ++i) {
                a0 = fmaf(dreg[0][i], pm[i], a0);
                a1 = fmaf(dreg[1][i], pp[i], a1);
            }
            v[0] = ok[0] ? fminf(fmaxf(a0, 0.0f), 1.0f) : 0.0f;
            v[1] = ok[1] ? fminf(fmaxf(a1, 0.0f), 1.0f) : 0.0f;
        }
        {   // o=2..5 from own plane in LDS
            const float (*L)[PLANE] = lds[buf];
#pragma unroll
            for (int o = 2; o < NCH; ++o) {
                float a = 0.0f;
                const int n = nbl[o - 2];
                if (ok[o]) {
#pragma unroll
                    for (int i = 0; i < NCH; ++i)
                        a = fmaf(dreg[o][i], L[i][n], a);
                    v[o] = fminf(fmaxf(a, 0.0f), 1.0f);
                } else {
                    v[o] = 0.0f;
                }
            }
        }

#pragma unroll
        for (int o = 0; o < NCH; ++o) {
            st_coh(&nxt[o * CH_STRIDE + cell], v[o]);   // publish to L3
            lds[buf ^ 1][o][tid] = v[o];                // own-plane copy
            myv[o] = v[o];
        }

        if (is_target) {
            const float s = v[0] + v[1] + v[2] + v[3] + v[4] + v[5];
            if (s > 0.01f)
                st_cohi(&flags[F_DONE], 1);
        }

        __syncthreads();                     // drain all waves' sc1 stores + LDS
        grid_barrier(t + 2, flags, &smem_done);
        __syncthreads();                     // publish smem_done; barrier complete

        float* tmp = cur; cur = nxt; nxt = tmp;
        buf ^= 1;
    }

    // record freeze point for the fill kernel (kernel-end flush publishes)
    if (xb == 0 && tid == 0) {
        flags[F_TFREEZE] = t;        // slices 0..t written by the stepper
        flags[F_PARITY]  = t & 1;    // frozen phi lives in (t&1) ? phi_b : phi_a
    }
}

// Fat fill kernel: slices t_freeze+1 .. maxit-1 all equal the frozen phi.
__global__ void fill_kernel(const int* __restrict__ flags,
                            const float* __restrict__ phi_a,
                            const float* __restrict__ phi_b,
                            float4* __restrict__ out,
                            int total4)
{
    const int idx4 = blockIdx.x * blockDim.x + threadIdx.x;
    if (idx4 >= total4) return;
    const int t_freeze = flags[F_TFREEZE];
    const int t = idx4 / (STEP_STRIDE / 4);
    if (t <= t_freeze) return;
    const int r4 = idx4 - t * (STEP_STRIDE / 4);
    const float4* frozen = (const float4*)(flags[F_PARITY] ? phi_b : phi_a);
    out[idx4] = frozen[r4];
}

extern "C" void kernel_launch(void* const* d_in, const int* in_sizes, int n_in,
                              void* d_out, int out_size, void* d_ws, size_t ws_size,
                              hipStream_t stream)
{
    const float* D   = (const float*)d_in[0];
    const int* sx    = (const int*)d_in[1];
    const int* sy    = (const int*)d_in[2];
    const int* sz    = (const int*)d_in[3];
    const int* ex    = (const int*)d_in[4];
    const int* ey    = (const int*)d_in[5];
    const int* ez    = (const int*)d_in[6];
    const int* maxit = (const int*)d_in[7];
    float* out = (float*)d_out;

    float* phi_a = (float*)d_ws;
    float* phi_b = phi_a + (size_t)NCH * NCELL;
    int* flags   = (int*)(phi_b + (size_t)NCH * NCELL);

    void* args[] = { &D, &sx, &sy, &sz, &ex, &ey, &ez, &maxit,
                     &out, &phi_a, &phi_b, &flags };

    // 32 blocks x 1024 threads = 1 thread/cell, block = x-plane. Cooperative
    // launch guarantees co-residency for the flat-flag spin barrier.
    hipLaunchCooperativeKernel(
        (void*)BEMNA_V7_2_PhaseSpace_44117904064519_kernel,
        dim3(NBLOCKS), dim3(NTHREADS), args, 0, stream);

    const int total4 = out_size / 4;
    const int fill_blocks = (total4 + 255) / 256;
    fill_kernel<<<dim3(fill_blocks), dim3(256), 0, stream>>>(
        flags, phi_a, phi_b, (float4*)out, total4);
}

// Round 4
// 479.370 us; speedup vs baseline: 3.7437x; 1.1255x over previous
//
#include <hip/hip_runtime.h>

#define NCH 6
#define NX 32
#define PLANE 1024                 // 32*32 cells per x-plane
#define NCELL (NX * PLANE)
#define CH_STRIDE NCELL
#define STEP_STRIDE (NCH * NCELL)
#define NBLOCKS NX                 // one block per x-plane
#define NTHREADS PLANE

// flags layout (ints) in ws after phi_a|phi_b. All cross-block flags are
// accessed with system-scope relaxed atomics -> live at the L3 coherence
// point, no L2 coherence traffic. Slots padded to one 64B line each.
#define F_DONE 0
#define F_TFREEZE 1
#define F_PARITY 2
#define F_GEN 16
#define F_SLOTS 32                 // slot b at F_SLOTS + b*16, b in [0,32)

__device__ __forceinline__ float ld_coh(const float* p) {
    return __hip_atomic_load(p, __ATOMIC_RELAXED, __HIP_MEMORY_SCOPE_SYSTEM);
}
__device__ __forceinline__ void st_coh(float* p, float v) {
    __hip_atomic_store(p, v, __ATOMIC_RELAXED, __HIP_MEMORY_SCOPE_SYSTEM);
}
__device__ __forceinline__ int ld_cohi(const int* p) {
    return __hip_atomic_load(p, __ATOMIC_RELAXED, __HIP_MEMORY_SCOPE_SYSTEM);
}
__device__ __forceinline__ void st_cohi(int* p, int v) {
    __hip_atomic_store(p, v, __ATOMIC_RELAXED, __HIP_MEMORY_SCOPE_SYSTEM);
}

// Flat-flag grid barrier: no atomic RMW (R2: 128 RMWs on one line ~16us/step),
// no acquire/release cache ops (all shared data is system-scope already).
// Caller must __syncthreads() BEFORE (drains each wave's sc1 stores to the L3
// coherence point) and AFTER (publishes smem_done block-wide).
// want is monotonically increasing; ws re-poison (0xAAAAAAAA = negative int)
// makes the signed >= comparisons safe at bootstrap — no explicit init needed.
__device__ __forceinline__ void grid_barrier(int want, int* flags, int* smem_done) {
    if (blockIdx.x == 0) {
        if (threadIdx.x < 64) {          // master wave polls all slots in parallel
            const int idx = (int)threadIdx.x & 31;
            const int* slot = &flags[F_SLOTS + idx * 16];
            for (;;) {
                const int v = (idx == 0) ? want : ld_cohi(slot);  // block 0 arrives implicitly
                if (__ballot(v >= want) == ~0ull) break;
                __builtin_amdgcn_s_sleep(1);
            }
            if (threadIdx.x == 0) {
                st_cohi(&flags[F_GEN], want);
                *smem_done = (ld_cohi(&flags[F_DONE]) == 1);
            }
        }
    } else if (threadIdx.x == 0) {
        st_cohi(&flags[F_SLOTS + (int)blockIdx.x * 16], want);
        while (ld_cohi(&flags[F_GEN]) < want)
            __builtin_amdgcn_s_sleep(1);
        *smem_done = (ld_cohi(&flags[F_DONE]) == 1);
    }
}

// One block per x-plane: y/z neighbor channels (o=2..5) are intra-block -> LDS;
// only x+-1 planes (o=0,1) cross blocks -> 12 system-scope loads/thread/step.
// NOTE: regular (non-cooperative) launch. Co-residency of 32 blocks with
// __launch_bounds__(1024,1) on 256 CUs is guaranteed by capacity (grid << CU
// count); R3 showed ~250us of non-stepper time that we attribute to the
// cooperative-launch graph node, so this round isolates that variable.
__global__ void __launch_bounds__(NTHREADS, 1)
BEMNA_V7_2_PhaseSpace_44117904064519_kernel(
    const float* __restrict__ D,
    const int* __restrict__ sx_p, const int* __restrict__ sy_p,
    const int* __restrict__ sz_p, const int* __restrict__ ex_p,
    const int* __restrict__ ey_p, const int* __restrict__ ez_p,
    const int* __restrict__ maxit_p,
    float* __restrict__ out,
    float* __restrict__ phi_a,
    float* __restrict__ phi_b,
    int* __restrict__ flags)
{
    __shared__ float lds[2][NCH][PLANE];   // ping-pong plane buffers, 48 KB
    __shared__ int smem_done;

    const int tid = (int)threadIdx.x;      // y*32+z
    const int xb  = (int)blockIdx.x;       // plane index = x
    const int y = tid >> 5;
    const int z = tid & 31;
    const int cell = xb * PLANE + tid;

    const int sx = *sx_p, sy = *sy_p, sz = *sz_p;
    const int ex = *ex_p, ey = *ey_p, ez = *ez_p;
    const int maxit = *maxit_p;
    const bool is_seed   = (xb == sx) && (tid == ((sy << 5) | sz));
    const bool is_target = (xb == ex) && (tid == ((ey << 5) | ez));

    // o=0:+x shift reads (x-1); o=1 reads (x+1); o=2:(y-1); o=3:(y+1); o=4:(z-1); o=5:(z+1)
    const int  nbg[NCH] = { cell - PLANE, cell + PLANE, cell - 32, cell + 32, cell - 1, cell + 1 };
    const bool ok[NCH]  = { xb >= 1, xb <= NX - 2, y >= 1, y <= 30, z >= 1, z <= 30 };
    const int  nbl[4]   = { tid - 32, tid + 32, tid - 1, tid + 1 };  // for o=2..5 in LDS

    // D step-invariant: hoist 36 coefficients (plain loads, read-only input)
    float dreg[NCH][NCH];
#pragma unroll
    for (int o = 0; o < NCH; ++o)
#pragma unroll
        for (int i = 0; i < NCH; ++i)
            dreg[o][i] = ok[o] ? D[(size_t)(o * NCH + i) * CH_STRIDE + nbg[o]] + 0.95f : 0.0f;

    // ---- init: phi0 = seed cell all-ones ----
    float myv[NCH];
    float* cur = phi_a;
    float* nxt = phi_b;
    int buf = 0;
    const float init_v = is_seed ? 1.0f : 0.0f;
#pragma unroll
    for (int o = 0; o < NCH; ++o) {
        myv[o] = init_v;
        st_coh(&cur[o * CH_STRIDE + cell], init_v);
        lds[0][o][tid] = init_v;
    }
    if (tid == 0) smem_done = 0;
    __syncthreads();                      // drain init stores (vmcnt + lds)
    grid_barrier(1, flags, &smem_done);   // publish init planes (F_DONE poisoned != 1 -> false)
    __syncthreads();

    int t = 0;
    for (; t < maxit; ++t) {
        // issue cross-plane loads early to overlap with history stores
        float pm[NCH], pp[NCH];
#pragma unroll
        for (int i = 0; i < NCH; ++i) {
            pm[i] = ok[0] ? ld_coh(&cur[i * CH_STRIDE + cell - PLANE]) : 0.0f;
            pp[i] = ok[1] ? ld_coh(&cur[i * CH_STRIDE + cell + PLANE]) : 0.0f;
        }

        // history[t] = phi (pre-update) straight from registers
        float* outp = out + (size_t)t * STEP_STRIDE + cell;
#pragma unroll
        for (int o = 0; o < NCH; ++o)
            outp[o * CH_STRIDE] = myv[o];

        if (smem_done) break;   // uniform: published at previous barrier

        float v[NCH];
        {   // o=0,1 from adjacent planes (L3)
            float a0 = 0.0f, a1 = 0.0f;
#pragma unroll
            for (int i = 0; i < NCH; ++i) {
                a0 = fmaf(dreg[0][i], pm[i], a0);
                a1 = fmaf(dreg[1][i], pp[i], a1);
            }
            v[0] = ok[0] ? fminf(fmaxf(a0, 0.0f), 1.0f) : 0.0f;
            v[1] = ok[1] ? fminf(fmaxf(a1, 0.0f), 1.0f) : 0.0f;
        }
        {   // o=2..5 from own plane in LDS
            const float (*L)[PLANE] = lds[buf];
#pragma unroll
            for (int o = 2; o < NCH; ++o) {
                float a = 0.0f;
                const int n = nbl[o - 2];
                if (ok[o]) {
#pragma unroll
                    for (int i = 0; i < NCH; ++i)
                        a = fmaf(dreg[o][i], L[i][n], a);
                    v[o] = fminf(fmaxf(a, 0.0f), 1.0f);
                } else {
                    v[o] = 0.0f;
                }
            }
        }

#pragma unroll
        for (int o = 0; o < NCH; ++o) {
            st_coh(&nxt[o * CH_STRIDE + cell], v[o]);   // publish to L3
            lds[buf ^ 1][o][tid] = v[o];                // own-plane copy
            myv[o] = v[o];
        }

        if (is_target) {
            const float s = v[0] + v[1] + v[2] + v[3] + v[4] + v[5];
            if (s > 0.01f)
                st_cohi(&flags[F_DONE], 1);
        }

        __syncthreads();                     // drain all waves' sc1 stores + LDS
        grid_barrier(t + 2, flags, &smem_done);
        __syncthreads();                     // publish smem_done; barrier complete

        float* tmp = cur; cur = nxt; nxt = tmp;
        buf ^= 1;
    }

    // record freeze point for the fill kernel (kernel-end flush publishes)
    if (xb == 0 && tid == 0) {
        flags[F_TFREEZE] = t;        // slices 0..t written by the stepper
        flags[F_PARITY]  = t & 1;    // frozen phi lives in (t&1) ? phi_b : phi_a
    }
}

// Fat fill kernel: slices t_freeze+1 .. maxit-1 all equal the frozen phi.
__global__ void fill_kernel(const int* __restrict__ flags,
                            const float* __restrict__ phi_a,
                            const float* __restrict__ phi_b,
                            float4* __restrict__ out,
                            int total4)
{
    const int idx4 = blockIdx.x * blockDim.x + threadIdx.x;
    if (idx4 >= total4) return;
    const int t_freeze = flags[F_TFREEZE];
    const int t = idx4 / (STEP_STRIDE / 4);
    if (t <= t_freeze) return;
    const int r4 = idx4 - t * (STEP_STRIDE / 4);
    const float4* frozen = (const float4*)(flags[F_PARITY] ? phi_b : phi_a);
    out[idx4] = frozen[r4];
}

extern "C" void kernel_launch(void* const* d_in, const int* in_sizes, int n_in,
                              void* d_out, int out_size, void* d_ws, size_t ws_size,
                              hipStream_t stream)
{
    const float* D   = (const float*)d_in[0];
    const int* sx    = (const int*)d_in[1];
    const int* sy    = (const int*)d_in[2];
    const int* sz    = (const int*)d_in[3];
    const int* ex    = (const int*)d_in[4];
    const int* ey    = (const int*)d_in[5];
    const int* ez    = (const int*)d_in[6];
    const int* maxit = (const int*)d_in[7];
    float* out = (float*)d_out;

    float* phi_a = (float*)d_ws;
    float* phi_b = phi_a + (size_t)NCH * NCELL;
    int* flags   = (int*)(phi_b + (size_t)NCH * NCELL);

    // 32 blocks x 1024 threads = 1 thread/cell, block = x-plane. Regular
    // launch (NOT cooperative): co-residency by capacity, barrier hand-rolled.
    BEMNA_V7_2_PhaseSpace_44117904064519_kernel<<<dim3(NBLOCKS), dim3(NTHREADS), 0, stream>>>(
        D, sx, sy, sz, ex, ey, ez, maxit, out, phi_a, phi_b, flags);

    const int total4 = out_size / 4;
    const int fill_blocks = (total4 + 255) / 256;
    fill_kernel<<<dim3(fill_blocks), dim3(256), 0, stream>>>(
        flags, phi_a, phi_b, (float4*)out, total4);
}